// Round 16
// baseline (408.213 us; speedup 1.0000x reference)
//
#include <hip/hip_runtime.h>
#include <hip/hip_bf16.h>
#include <stdint.h>

#define B_   8
#define S_   1042
#define H_   768
#define NH_  12
#define HD_  64
#define MLP_ 2048
#define T_   (B_*S_)    // 8336 tokens
#define MP_  8448       // tokens padded to 66*128 (and 33*256)
#define SP_  1088       // seq padded to 17*64
#define EPS_ 1e-6f
#define PSLICE ((long)96 * SP_ * 64)   // partial-buffer stride (elements)

typedef __attribute__((ext_vector_type(8))) short bf16x8v;
typedef __attribute__((ext_vector_type(4))) float f32x4;
typedef __hip_bfloat16 bf16;

typedef __attribute__((address_space(1))) const void gas_void;
typedef __attribute__((address_space(3))) void las_void;

__device__ inline void gload_lds16(const void* g, void* l) {
  __builtin_amdgcn_global_load_lds((gas_void*)g, (las_void*)l, 16, 0, 0);
}

#define BARRIER asm volatile("s_barrier" ::: "memory")
#define VMCNT2  asm volatile("s_waitcnt vmcnt(2)" ::: "memory")
#define VMCNT0  asm volatile("s_waitcnt vmcnt(0)" ::: "memory")

// ---------------- weight convert + transpose (LDS-tiled): out[n*K+k] = W[k*N+n] ----------------
__global__ __launch_bounds__(256) void wcvt_t(const float* __restrict__ W, bf16* __restrict__ o,
                                              int K, int N) {
  __shared__ float tile[32][33];
  int kt = blockIdx.x, nt = blockIdx.y;
  int t = threadIdx.x;
  int r = t >> 5, c = t & 31;
#pragma unroll
  for (int i = 0; i < 4; i++)
    tile[i * 8 + r][c] = W[(long)(kt * 32 + i * 8 + r) * N + nt * 32 + c];
  __syncthreads();
#pragma unroll
  for (int i = 0; i < 4; i++)
    o[(long)(nt * 32 + i * 8 + r) * K + kt * 32 + c] = __float2bfloat16(tile[c][i * 8 + r]);
}

// ---------------- gate/up interleaved weight transpose ----------------
__global__ __launch_bounds__(256) void wcvt_gu(const float* __restrict__ Wg,
                                               const float* __restrict__ Wu,
                                               bf16* __restrict__ o) {
  __shared__ float tile[32][33];
  int kt = blockIdx.x, nt = blockIdx.y;   // k-tile (24), n-tile (128)
  int t = threadIdx.x;
  int r = t >> 5, c = t & 31;
  const float* src = (c < 16) ? Wg : Wu;
  int col = nt * 16 + (c & 15);
#pragma unroll
  for (int i = 0; i < 4; i++)
    tile[i * 8 + r][c] = src[(long)(kt * 32 + i * 8 + r) * MLP_ + col];
  __syncthreads();
#pragma unroll
  for (int i = 0; i < 4; i++)
    o[(long)(nt * 32 + i * 8 + r) * 768 + kt * 32 + c] = __float2bfloat16(tile[c][i * 8 + r]);
}

// ---------------- rmsnorm (768 wide), fp32 in -> bf16 out; GATE: fused head-gate ----------------
template <int GATE>
__global__ __launch_bounds__(256) void rmsnorm_k(const float* __restrict__ x,
                                                 const float* __restrict__ w,
                                                 bf16* __restrict__ o,
                                                 const float* __restrict__ gW,
                                                 const float* __restrict__ gb,
                                                 float* __restrict__ gate, int Mreal) {
  int row = blockIdx.x;
  bf16* orow = o + (long)row * H_;
  int t = threadIdx.x;
  if (row >= Mreal) {
    for (int i = t; i < H_; i += 256) orow[i] = __float2bfloat16(0.f);
    return;
  }
  const float* xr = x + (long)row * H_;
  float v0 = xr[t], v1 = xr[t + 256], v2 = xr[t + 512];
  float s = v0 * v0 + v1 * v1 + v2 * v2;
  for (int off = 32; off; off >>= 1) s += __shfl_down(s, off);
  __shared__ float red[4];
  __shared__ float gred[4][12];
  if ((t & 63) == 0) red[t >> 6] = s;
  __syncthreads();
  float tot = red[0] + red[1] + red[2] + red[3];
  float inv = rsqrtf(tot * (1.f / H_) + EPS_);
  float h0 = v0 * inv * w[t], h1 = v1 * inv * w[t + 256], h2 = v2 * inv * w[t + 512];
  orow[t]       = __float2bfloat16(h0);
  orow[t + 256] = __float2bfloat16(h1);
  orow[t + 512] = __float2bfloat16(h2);
  if (GATE) {
    const float* g0 = gW + (long)t * 12;
    const float* g1 = gW + (long)(t + 256) * 12;
    const float* g2 = gW + (long)(t + 512) * 12;
    float g[12];
#pragma unroll
    for (int n = 0; n < 12; n++) g[n] = h0 * g0[n] + h1 * g1[n] + h2 * g2[n];
#pragma unroll
    for (int n = 0; n < 12; n++) {
      float v = g[n];
      v += __shfl_xor(v, 1); v += __shfl_xor(v, 2); v += __shfl_xor(v, 4);
      v += __shfl_xor(v, 8); v += __shfl_xor(v, 16); v += __shfl_xor(v, 32);
      if ((t & 63) == 0) gred[t >> 6][n] = v;
    }
    __syncthreads();
    if (t < 12) {
      float s4 = gred[0][t] + gred[1][t] + gred[2][t] + gred[3][t];
      gate[(long)row * 12 + t] = 1.f / (1.f + __expf(-(s4 + gb[t])));
    }
  }
}

// ======== 256x256 8-phase GEMM, BK=32, 8 waves, 64KB LDS (sound sync, r15) ========
// L2-locality remap: within a k-slice, tiles are ordered in bm-groups of 8,
// bm-minor -> one XCD's contiguous chunk reuses each B-panel 8x back-to-back
// while ~8 A-panels (3.1MB) stay L2-resident (working set ~3.9MB <= 4MB L2).
template <int EPI, int KT, int LD, int NKS>
__global__ __launch_bounds__(512) void gemm256(
    const bf16* __restrict__ A, const bf16* __restrict__ Bt, void* __restrict__ Out,
    const float* __restrict__ resid, const float* __restrict__ scale,
    int N, int nbn, int Mreal, bf16* __restrict__ alt3) {
  __shared__ __align__(16) bf16 lds[2][4][128 * 32];   // 64 KB
  int tid = threadIdx.x;
  int lane = tid & 63, wid = tid >> 6;
  int wr = wid >> 2, wc = wid & 3;         // wave grid 2(M) x 4(N)
  int lr = lane & 15, lg = lane >> 4;

  // XCD-bijective block swizzle (m204)
  int nwg = gridDim.x;
  int bid = blockIdx.x;
  int q = nwg >> 3, r8 = nwg & 7;
  int xcd = bid & 7, idx = bid >> 3;
  int wg = (xcd < r8 ? xcd * (q + 1) : r8 * (q + 1) + (xcd - r8) * q) + idx;

  int bps = nwg;
  int ks = 0;
  if (NKS > 1) {
    bps = nwg / NKS;                       // blocks per k-slice
    ks = wg / bps;
    wg = wg - ks * bps;
    A += (long)ks * KT * 32;
    Bt += (long)ks * KT * 32;
  }
  // L2 tile remap: bm-groups of 8, bm-minor (bijective)
  int nbm = bps / nbn;
  int gm = wg / (8 * nbn);
  int rem = wg - gm * 8 * nbn;
  int gh = nbm - gm * 8; if (gh > 8) gh = 8;
  int bm = gm * 8 + rem % gh;
  int bn = rem / gh;

  // hoisted ds-read base pointers: (row>>1)&3 == (lr>>1)&3 for every fragment row
  const bf16 *aP[2], *bP[2];
  {
    int off = lr * 32 + ((lg ^ ((lr >> 1) & 3)) * 8);
#pragma unroll
    for (int b = 0; b < 2; b++) {
      aP[b] = &lds[b][wr][off];
      bP[b] = &lds[b][2 + (wc >> 1)][(wc & 1) * 2048 + off];
    }
  }
  // hoisted staging pointers (inverse-swizzled global source)
  int srow = tid >> 2;                         // 0..127
  int cc = (tid & 3) ^ ((srow >> 1) & 3);
  const bf16 *aB[2], *bB[2];
#pragma unroll
  for (int h = 0; h < 2; h++) {
    aB[h] = A + ((long)bm * 256 + h * 128 + srow) * LD + cc * 8;
    bB[h] = Bt + ((long)bn * 256 + h * 128 + srow) * LD + cc * 8;
  }

#define STA(buf, half, kt) gload_lds16(aB[half] + (kt) * 32, &lds[buf][half][tid * 8]);
#define STB(buf, half, kt) gload_lds16(bB[half] + (kt) * 32, &lds[buf][2 + (half)][tid * 8]);

  f32x4 z; z[0] = z[1] = z[2] = z[3] = 0.f;
  f32x4 acc[8][4];
#pragma unroll
  for (int mi = 0; mi < 8; mi++)
#pragma unroll
    for (int ni = 0; ni < 4; ni++) acc[mi][ni] = z;

  bf16x8v bf[4];
  bf16x8v af[2];

  // prologue: tile0 full + tile1 B-halves (6 insts; vmcnt2 then barrier -> sound)
  STA(0, 0, 0); STA(0, 1, 0); STB(0, 0, 0); STB(0, 1, 0);
  STB(1, 0, 1); STB(1, 1, 1);
  VMCNT2;
  BARRIER;

#define PHASE(p, bb, STG, VM)                                                   \
  {                                                                             \
    if ((p) == 0) {                                                             \
      _Pragma("unroll") for (int ni = 0; ni < 4; ni++)                          \
        bf[ni] = *(const bf16x8v*)(bP[bb] + ni * 512);                          \
    }                                                                           \
    af[0] = *(const bf16x8v*)(aP[bb] + (2 * (p)) * 512);                        \
    af[1] = *(const bf16x8v*)(aP[bb] + (2 * (p) + 1) * 512);                    \
    STG;                                                                        \
    BARRIER;                                                                    \
    __builtin_amdgcn_s_setprio(1);                                              \
    _Pragma("unroll") for (int dm = 0; dm < 2; dm++)                            \
      _Pragma("unroll") for (int ni = 0; ni < 4; ni++)                          \
        acc[2 * (p) + dm][ni] = __builtin_amdgcn_mfma_f32_16x16x32_bf16(        \
            af[dm], bf[ni], acc[2 * (p) + dm][ni], 0, 0, 0);                    \
    __builtin_amdgcn_s_setprio(0);                                              \
    if (VM) { VMCNT2; BARRIER; }                                                \
  }

#define ITERBODY(i)                                                             \
  {                                                                             \
    int u = 2 * (i) + 1;                                                        \
    int t2 = (2 * (i) + 2 < KT) ? 2 * (i) + 2 : KT - 1;                         \
    int t3 = (2 * (i) + 3 < KT) ? 2 * (i) + 3 : KT - 1;                         \
    PHASE(0, 0, STA(1, 0, u), 0);                                               \
    PHASE(1, 0, STA(1, 1, u), 0);                                               \
    PHASE(2, 0, STB(0, 0, t2), 0);                                              \
    PHASE(3, 0, STB(0, 1, t2), 1);                                              \
    PHASE(0, 1, STA(0, 0, t2), 0);                                              \
    PHASE(1, 1, STA(0, 1, t2), 0);                                              \
    PHASE(2, 1, STB(1, 0, t3), 0);                                              \
    PHASE(3, 1, STB(1, 1, t3), 1);                                              \
  }

  if (KT <= 12) {
#pragma unroll
    for (int i = 0; i < KT / 2; i++) ITERBODY(i);
  } else {
#pragma unroll 2
    for (int i = 0; i < KT / 2; i++) ITERBODY(i);
  }
  VMCNT0;   // drain redundant tail stages: nothing in flight at exit
#undef ITERBODY
#undef PHASE
#undef STA
#undef STB

  // epilogue
  long rowbase = (long)bm * 256 + wr * 128;
  int colbase = bn * 256 + wc * 64;
  if (EPI == 0) {
    bf16* O;
    if (NKS > 1) O = (ks < 3) ? (bf16*)Out + (long)ks * PSLICE : alt3;
    else O = (bf16*)Out;
#pragma unroll
    for (int mi = 0; mi < 8; mi++)
#pragma unroll
      for (int ni = 0; ni < 4; ni++)
#pragma unroll
        for (int r = 0; r < 4; r++)
          O[(rowbase + mi * 16 + lg * 4 + r) * N + colbase + ni * 16 + lr] =
              __float2bfloat16(acc[mi][ni][r]);
  } else if (EPI == 1) {
    float* O = (float*)Out;
#pragma unroll
    for (int ni = 0; ni < 4; ni++) {
      float sc = scale[colbase + ni * 16 + lr];
#pragma unroll
      for (int mi = 0; mi < 8; mi++)
#pragma unroll
        for (int r = 0; r < 4; r++) {
          long row = rowbase + mi * 16 + lg * 4 + r;
          long col = colbase + ni * 16 + lr;
          if (row < Mreal)
            O[row * N + col] = resid[row * N + col] + acc[mi][ni][r] * sc;
        }
    }
  } else {
    bf16* O = (bf16*)Out;
    int oc0 = colbase >> 1;
#pragma unroll
    for (int mi = 0; mi < 8; mi++)
#pragma unroll
      for (int p = 0; p < 2; p++)
#pragma unroll
        for (int r = 0; r < 4; r++) {
          float g = acc[mi][2 * p][r], u = acc[mi][2 * p + 1][r];
          float v = g / (1.f + __expf(-g)) * u;
          O[(rowbase + mi * 16 + lg * 4 + r) * 2048 + oc0 + p * 16 + lr] =
              __float2bfloat16(v);
        }
  }
}

// ---------------- MLP2 split-K reduce: out = x2 + (P0+P1+P2+P3)*mscale ----------------
__global__ __launch_bounds__(256) void mlp2_reduce(
    const bf16* __restrict__ p012, const bf16* __restrict__ p3,
    const float* __restrict__ x2, const float* __restrict__ mscale,
    float* __restrict__ out) {
  long i = (long)blockIdx.x * 256 + threadIdx.x;
  long row = i / 96;
  int c8 = (int)(i - row * 96) * 8;
  long off = row * 768 + c8;
  float a[8];
#pragma unroll
  for (int j = 0; j < 8; j++) a[j] = 0.f;
#pragma unroll
  for (int s = 0; s < 3; s++) {
    bf16x8v v = *(const bf16x8v*)(p012 + s * PSLICE + off);
#pragma unroll
    for (int j = 0; j < 8; j++) {
      short sv = v[j];
      a[j] += __bfloat162float(*reinterpret_cast<bf16*>(&sv));
    }
  }
  {
    bf16x8v v = *(const bf16x8v*)(p3 + off);
#pragma unroll
    for (int j = 0; j < 8; j++) {
      short sv = v[j];
      a[j] += __bfloat162float(*reinterpret_cast<bf16*>(&sv));
    }
  }
#pragma unroll
  for (int j = 0; j < 8; j++)
    out[off + j] = x2[off + j] + a[j] * mscale[c8 + j];
}

// ---------------- V transpose: qkv v-part -> vtf[(bh*64+d)*SP_+s]; zero pad cols ----------------
__global__ __launch_bounds__(256) void vtran(const bf16* __restrict__ qkv, bf16* __restrict__ vtf) {
  __shared__ bf16 tile[32][66];
  int st = blockIdx.x, bh = blockIdx.y;
  int bb = bh / NH_, h = bh - bb * NH_;
  int s0 = st * 32;
  int t = threadIdx.x;
  int si = t >> 6, d = t & 63;
#pragma unroll
  for (int i = 0; i < 8; i++) {
    int s = s0 + i * 4 + si;
    bf16 v = __float2bfloat16(0.f);
    if (s < S_) v = qkv[(long)(bb * S_ + s) * 2304 + 1536 + h * 64 + d];
    tile[i * 4 + si][d] = v;
  }
  __syncthreads();
  int dd = t >> 5, sj = t & 31;
#pragma unroll
  for (int i = 0; i < 8; i++) {
    int d2 = i * 8 + dd;
    vtf[((long)bh * 64 + d2) * SP_ + s0 + sj] = tile[sj][d2];
  }
}

// ---------------- qk rmsnorm + rope + scale (q scaled to base-2 exp units) ----------------
__global__ __launch_bounds__(768) void qkv_post(
    const bf16* __restrict__ qkv, const float* __restrict__ qw, const float* __restrict__ kw,
    const float* __restrict__ cosT, const float* __restrict__ sinT,
    bf16* __restrict__ qf, bf16* __restrict__ kf) {
  int tok = blockIdx.x;
  int bb = tok / S_, s = tok - bb * S_;
  int h = threadIdx.x >> 6, d = threadIdx.x & 63;
  const bf16* base = qkv + (long)tok * 2304 + h * 64 + d;
  float q = __bfloat162float(base[0]);
  float k = __bfloat162float(base[768]);
  float qs = q * q, ks = k * k;
  for (int off = 32; off; off >>= 1) {
    qs += __shfl_xor(qs, off);
    ks += __shfl_xor(ks, off);
  }
  q *= rsqrtf(qs * (1.f / 64.f) + EPS_) * qw[d];
  k *= rsqrtf(ks * (1.f / 64.f) + EPS_) * kw[d];
  if (s >= S_ - 1024) {
    int pos = s - (S_ - 1024);
    int i = d >> 1;
    float c = cosT[pos * 32 + i], sn = sinT[pos * 32 + i];
    float qp = __shfl_xor(q, 1), kp = __shfl_xor(k, 1);
    if (d & 1) { q = qp * sn + q * c; k = kp * sn + k * c; }
    else       { q = q * c - qp * sn; k = k * c - kp * sn; }
  }
  q *= 0.125f * 1.44269504088896f;  // fold log2(e): softmax done in base 2
  long o1 = ((long)(bb * NH_ + h) * SP_ + s) * 64 + d;
  qf[o1] = __float2bfloat16(q);
  kf[o1] = __float2bfloat16(k);
}

// swizzled LDS element offset for a [64][8x(8elem)] bf16 tile: row, colchunk cc
#define SWZ(row, cc) (((row) << 6) + ((((cc) ^ ((row) & 7))) << 3))

// ---------------- flash attention: 4 waves/block, 64 q-rows, KVBLK=64, LDS dbuf ----------------
// (round-10 proven config: 32 KB LDS, ~12 waves/CU)
// UNNORMALIZED softmax: after qk-rmsnorm ||q||=||k||=8 (RoPE is a rotation), so by
// Cauchy-Schwarz |score_base2| <= 8*8*0.125*log2(e) = 11.5 -> exp2 in [2^-11.5, 2^11.5],
// lsum in [0.36, 3.1e6]: no overflow, identical relative error. No max tracking needed.
__global__ __launch_bounds__(256) void attn_k(
    const bf16* __restrict__ qf, const bf16* __restrict__ kf, const bf16* __restrict__ vtf,
    const float* __restrict__ gate, bf16* __restrict__ attn_g) {
  __shared__ __align__(16) bf16 Ks[2][64 * 64];
  __shared__ __align__(16) bf16 Vs[2][64 * 64];
  int bid = blockIdx.x;                      // 1632 = 8 * 204
  int w = (bid & 7) * 204 + (bid >> 3);      // XCD-pinned: 12 bh per XCD
  int bh = w / 17, qb = w - bh * 17;
  int bb = bh / NH_, h = bh - bb * NH_;
  int tid = threadIdx.x;
  int lane = tid & 63, wv = tid >> 6;
  int lr = lane & 15, lg = lane >> 4;
  const bf16* qbase = qf + (long)bh * SP_ * 64;
  const bf16* kbase = kf + (long)bh * SP_ * 64;
  const bf16* vbase = vtf + (long)bh * 64 * SP_;

  int q_l = qb * 64 + wv * 16 + lr;          // q row this lane owns
  bf16x8v qB0 = *(const bf16x8v*)(qbase + (long)q_l * 64 + lg * 8);
  bf16x8v qB1 = *(const bf16x8v*)(qbase + (long)q_l * 64 + 32 + lg * 8);

  f32x4 z; z[0] = z[1] = z[2] = z[3] = 0.f;
  f32x4 acc[4] = {z, z, z, z};
  float tsacc = 0.f;                         // per-lane partial sum (16 of 64 ks per tile)

  auto stage = [&](int buf, int kidx) {
#pragma unroll
    for (int inst = 0; inst < 2; inst++) {
      int c = inst * 256 + tid;
      int row = c >> 3, slot = c & 7;
      int cc = slot ^ (row & 7);
      gload_lds16(kbase + (long)(kidx + row) * 64 + cc * 8, &Ks[buf][c * 8]);
    }
#pragma unroll
    for (int inst = 0; inst < 2; inst++) {
      int c = inst * 256 + tid;
      int row = c >> 3, slot = c & 7;
      int cc = slot ^ (row & 7);
      gload_lds16(vbase + (long)row * SP_ + kidx + cc * 8, &Vs[buf][c * 8]);
    }
  };

  stage(0, 0);
  VMCNT0;
  __syncthreads();
  int cur = 0;

  for (int kt = 0; kt < SP_ / 64; kt++) {
    int kidx = kt * 64;
    if (kt < SP_ / 64 - 1) stage(cur ^ 1, kidx + 64);

    f32x4 p[4];
    __builtin_amdgcn_s_setprio(1);
#pragma unroll
    for (int mt = 0; mt < 4; mt++) {
      int row = mt * 16 + lr;
      bf16x8v k0 = *(const bf16x8v*)&Ks[cur][SWZ(row, lg)];
      bf16x8v k1 = *(const bf16x8v*)&Ks[cur][SWZ(row, lg + 4)];
      f32x4 t = z;
      t = __builtin_amdgcn_mfma_f32_16x16x32_bf16(k0, qB0, t, 0, 0, 0);
      t = __builtin_amdgcn_mfma_f32_16x16x32_bf16(k1, qB1, t, 0, 0, 0);
      p[mt] = t;
    }
    __builtin_amdgcn_s_setprio(0);

    if (kidx + 64 > S_) {
#pragma unroll
      for (int mt = 0; mt < 4; mt++)
#pragma unroll
        for (int r = 0; r < 4; r++)
          if (kidx + mt * 16 + lg * 4 + r >= S_) p[mt][r] = -1e30f;
    }

    // unnormalized: p = exp2(score), accumulate per-lane partial sum
#pragma unroll
    for (int mt = 0; mt < 4; mt++)
#pragma unroll
      for (int r = 0; r < 4; r++) {
        float e = exp2f(p[mt][r]);
        p[mt][r] = e;
        tsacc += e;
      }

    uint32_t w0[4], w1[4];
#pragma unroll
    for (int mt = 0; mt < 4; mt++) {
      asm("v_cvt_pk_bf16_f32 %0, %1, %2" : "=v"(w0[mt]) : "v"(p[mt][0]), "v"(p[mt][1]));
      asm("v_cvt_pk_bf16_f32 %0, %1, %2" : "=v"(w1[mt]) : "v"(p[mt][2]), "v"(p[mt][3]));
    }
    bf16x8v aP[2];
#pragma unroll
    for (int t2 = 0; t2 < 2; t2++) {
      union { uint32_t u[4]; bf16x8v v; } cvt;
#pragma unroll
      for (int wd = 0; wd < 4; wd++) {
        uint32_t a = (wd & 1) ? w1[2 * t2] : w0[2 * t2];
        uint32_t b = (wd & 1) ? w1[2 * t2 + 1] : w0[2 * t2 + 1];
        uint32_t val = (lg & 2) ? b : a;
        int src = ((lg & 1) * 2 + (wd >> 1)) * 16 + lr;
        cvt.u[wd] = (uint32_t)__shfl((int)val, src);
      }
      aP[t2] = cvt.v;
    }
    __builtin_amdgcn_s_setprio(1);
#pragma unroll
    for (int t2 = 0; t2 < 2; t2++)
#pragma unroll
      for (int dt = 0; dt < 4; dt++) {
        int row = dt * 16 + lr;
        bf16x8v vB = *(const bf16x8v*)&Vs[cur][SWZ(row, t2 * 4 + lg)];
        acc[dt] = __builtin_amdgcn_mfma_f32_16x16x32_bf16(aP[t2], vB, acc[dt], 0, 0, 0);
      }
    __builtin_amdgcn_s_setprio(0);

    VMCNT0;
    __syncthreads();
    cur ^= 1;
  }

  // single cross-lane lsum reduce at the end
  tsacc += __shfl_xor(tsacc, 16);
  tsacc += __shfl_xor(tsacc, 32);
  float norm = 0.f;
  if (q_l < S_) norm = gate[((long)bb * S_ + q_l) * 12 + h] / tsacc;
  float nr[4];
#pragma unroll
  for (int r = 0; r < 4; r++) nr[r] = __shfl(norm, lg * 4 + r);
#pragma unroll
  for (int dt = 0; dt < 4; dt++)
#pragma unroll
    for (int r = 0; r < 4; r++) {
      int qr = qb * 64 + wv * 16 + lg * 4 + r;
      if (qr < S_)
        attn_g[((long)bb * S_ + qr) * H_ + h * 64 + dt * 16 + lr] =
            __float2bfloat16(acc[dt][r] * nr[r]);
    }
}

extern "C" void kernel_launch(void* const* d_in, const int* in_sizes, int n_in,
                              void* d_out, int out_size, void* d_ws, size_t ws_size,
                              hipStream_t stream) {
  const float* x    = (const float*)d_in[0];
  const float* cosT = (const float*)d_in[1];
  const float* sinT = (const float*)d_in[2];
  const float* Wq   = (const float*)d_in[3];
  const float* Wk   = (const float*)d_in[4];
  const float* Wv   = (const float*)d_in[5];
  const float* Wo   = (const float*)d_in[6];
  const float* qnw  = (const float*)d_in[7];
  const float* knw  = (const float*)d_in[8];
  const float* gW   = (const float*)d_in[9];
  const float* gb   = (const float*)d_in[10];
  const float* n1w  = (const float*)d_in[11];
  const float* n2w  = (const float*)d_in[12];
  const float* Wg   = (const float*)d_in[13];
  const float* Wu   = (const float*)d_in[14];
  const float* Wd   = (const float*)d_in[15];
  const float* ascale = (const float*)d_in[16];
  const float* mscale = (const float*)d_in[17];

  char* ws = (char*)d_ws;
  size_t off = 0;
  auto alloc = [&](size_t bytes) {
    char* p = ws + off;
    off += (bytes + 255) & ~(size_t)255;
    return p;
  };
  bf16* h_pad  = (bf16*)alloc((size_t)MP_ * H_ * 2);      // reused as h2
  bf16* wqkv_t = (bf16*)alloc((size_t)2304 * 768 * 2);
  bf16* wo_t   = (bf16*)alloc((size_t)768 * 768 * 2);
  bf16* wgu_t  = (bf16*)alloc((size_t)4096 * 768 * 2);    // gate/up 16-col interleaved
  bf16* wdn_t  = (bf16*)alloc((size_t)768 * 2048 * 2);
  bf16* qkv    = (bf16*)alloc((size_t)MP_ * 2304 * 2);    // reused as mlpin (MP_*2048)
  bf16* qfb    = (bf16*)alloc((size_t)PSLICE * 2);        // reused: MLP2 partial 0
  bf16* kfb    = (bf16*)alloc((size_t)PSLICE * 2);        // reused: MLP2 partial 1
  bf16* vtfb   = (bf16*)alloc((size_t)PSLICE * 2);        // reused: MLP2 partial 2
  float* gateb = (float*)alloc((size_t)T_ * 12 * 4);
  bf16* attn_g = (bf16*)alloc((size_t)MP_ * H_ * 2);      // reused: MLP2 partial 3
  float* x2    = (float*)alloc((size_t)T_ * H_ * 4);
  bf16* mlpin  = qkv;

  // weight conversion
  auto wc = [&](const float* W, bf16* o, int K, int N) {
    wcvt_t<<<dim3(K / 32, N / 32), 256, 0, stream>>>(W, o, K, N);
  };
  wc(Wq, wqkv_t, 768, 768);
  wc(Wk, wqkv_t + 768 * 768, 768, 768);
  wc(Wv, wqkv_t + 2 * 768 * 768, 768, 768);
  wc(Wo, wo_t, 768, 768);
  wc(Wd, wdn_t, 2048, 768);
  wcvt_gu<<<dim3(24, 128), 256, 0, stream>>>(Wg, Wu, wgu_t);

  rmsnorm_k<1><<<MP_, 256, 0, stream>>>(x, n1w, h_pad, gW, gb, gateb, T_);

  // QKV: M=8448 N=2304 K=768
  gemm256<0, 24, 768, 1><<<9 * 33, 512, 0, stream>>>(h_pad, wqkv_t, qkv, nullptr, nullptr,
                                                     2304, 9, MP_, nullptr);

  qkv_post<<<T_, 768, 0, stream>>>(qkv, qnw, knw, cosT, sinT, qfb, kfb);
  vtran<<<dim3(34, 96), 256, 0, stream>>>(qkv, vtfb);

  attn_k<<<1632, 256, 0, stream>>>(qfb, kfb, vtfb, gateb, attn_g);

  // Wo: M=8448 N=768 K=768, fp32 resid+scale epilogue
  gemm256<1, 24, 768, 1><<<3 * 33, 512, 0, stream>>>(attn_g, wo_t, x2, x, ascale,
                                                     768, 3, T_, nullptr);

  rmsnorm_k<0><<<MP_, 256, 0, stream>>>(x2, n2w, h_pad, nullptr, nullptr, nullptr, T_);

  // MLP1: M=8448 N=4096 K=768, silu-fused
  gemm256<2, 24, 768, 1><<<16 * 33, 512, 0, stream>>>(h_pad, wgu_t, mlpin, nullptr, nullptr,
                                                      4096, 16, MP_, nullptr);

  // MLP2: split-K=4 (slice K=512, KT=16), 396 blocks; bf16 partials -> reduce
  gemm256<0, 16, 2048, 4><<<4 * 3 * 33, 512, 0, stream>>>(mlpin, wdn_t, qfb, nullptr, nullptr,
                                                          768, 3, MP_, attn_g);
  mlp2_reduce<<<(T_ * 96) / 256, 256, 0, stream>>>(qfb, attn_g, x2, mscale, (float*)d_out);
}

// Round 17
// 391.818 us; speedup vs baseline: 1.0418x; 1.0418x over previous
//
#include <hip/hip_runtime.h>
#include <hip/hip_bf16.h>
#include <stdint.h>

#define B_   8
#define S_   1042
#define H_   768
#define NH_  12
#define HD_  64
#define MLP_ 2048
#define T_   (B_*S_)    // 8336 tokens
#define MP_  8448       // tokens padded to 66*128 (and 33*256)
#define SP_  1088       // seq padded to 17*64
#define EPS_ 1e-6f
#define PSLICE ((long)96 * SP_ * 64)   // partial-buffer stride (elements)

typedef __attribute__((ext_vector_type(8))) short bf16x8v;
typedef __attribute__((ext_vector_type(4))) float f32x4;
typedef __hip_bfloat16 bf16;

typedef __attribute__((address_space(1))) const void gas_void;
typedef __attribute__((address_space(3))) void las_void;

__device__ inline void gload_lds16(const void* g, void* l) {
  __builtin_amdgcn_global_load_lds((gas_void*)g, (las_void*)l, 16, 0, 0);
}

#define BARRIER asm volatile("s_barrier" ::: "memory")
#define VMCNT2  asm volatile("s_waitcnt vmcnt(2)" ::: "memory")
#define VMCNT0  asm volatile("s_waitcnt vmcnt(0)" ::: "memory")

// ---------------- weight convert + transpose (LDS-tiled): out[n*K+k] = W[k*N+n] ----------------
__global__ __launch_bounds__(256) void wcvt_t(const float* __restrict__ W, bf16* __restrict__ o,
                                              int K, int N) {
  __shared__ float tile[32][33];
  int kt = blockIdx.x, nt = blockIdx.y;
  int t = threadIdx.x;
  int r = t >> 5, c = t & 31;
#pragma unroll
  for (int i = 0; i < 4; i++)
    tile[i * 8 + r][c] = W[(long)(kt * 32 + i * 8 + r) * N + nt * 32 + c];
  __syncthreads();
#pragma unroll
  for (int i = 0; i < 4; i++)
    o[(long)(nt * 32 + i * 8 + r) * K + kt * 32 + c] = __float2bfloat16(tile[c][i * 8 + r]);
}

// ---------------- gate/up interleaved weight transpose ----------------
__global__ __launch_bounds__(256) void wcvt_gu(const float* __restrict__ Wg,
                                               const float* __restrict__ Wu,
                                               bf16* __restrict__ o) {
  __shared__ float tile[32][33];
  int kt = blockIdx.x, nt = blockIdx.y;   // k-tile (24), n-tile (128)
  int t = threadIdx.x;
  int r = t >> 5, c = t & 31;
  const float* src = (c < 16) ? Wg : Wu;
  int col = nt * 16 + (c & 15);
#pragma unroll
  for (int i = 0; i < 4; i++)
    tile[i * 8 + r][c] = src[(long)(kt * 32 + i * 8 + r) * MLP_ + col];
  __syncthreads();
#pragma unroll
  for (int i = 0; i < 4; i++)
    o[(long)(nt * 32 + i * 8 + r) * 768 + kt * 32 + c] = __float2bfloat16(tile[c][i * 8 + r]);
}

// ---------------- rmsnorm (768 wide), fp32 in -> bf16 out; GATE: fused head-gate ----------------
template <int GATE>
__global__ __launch_bounds__(256) void rmsnorm_k(const float* __restrict__ x,
                                                 const float* __restrict__ w,
                                                 bf16* __restrict__ o,
                                                 const float* __restrict__ gW,
                                                 const float* __restrict__ gb,
                                                 float* __restrict__ gate, int Mreal) {
  int row = blockIdx.x;
  bf16* orow = o + (long)row * H_;
  int t = threadIdx.x;
  if (row >= Mreal) {
    for (int i = t; i < H_; i += 256) orow[i] = __float2bfloat16(0.f);
    return;
  }
  const float* xr = x + (long)row * H_;
  float v0 = xr[t], v1 = xr[t + 256], v2 = xr[t + 512];
  float s = v0 * v0 + v1 * v1 + v2 * v2;
  for (int off = 32; off; off >>= 1) s += __shfl_down(s, off);
  __shared__ float red[4];
  __shared__ float gred[4][12];
  if ((t & 63) == 0) red[t >> 6] = s;
  __syncthreads();
  float tot = red[0] + red[1] + red[2] + red[3];
  float inv = rsqrtf(tot * (1.f / H_) + EPS_);
  float h0 = v0 * inv * w[t], h1 = v1 * inv * w[t + 256], h2 = v2 * inv * w[t + 512];
  orow[t]       = __float2bfloat16(h0);
  orow[t + 256] = __float2bfloat16(h1);
  orow[t + 512] = __float2bfloat16(h2);
  if (GATE) {
    const float* g0 = gW + (long)t * 12;
    const float* g1 = gW + (long)(t + 256) * 12;
    const float* g2 = gW + (long)(t + 512) * 12;
    float g[12];
#pragma unroll
    for (int n = 0; n < 12; n++) g[n] = h0 * g0[n] + h1 * g1[n] + h2 * g2[n];
#pragma unroll
    for (int n = 0; n < 12; n++) {
      float v = g[n];
      v += __shfl_xor(v, 1); v += __shfl_xor(v, 2); v += __shfl_xor(v, 4);
      v += __shfl_xor(v, 8); v += __shfl_xor(v, 16); v += __shfl_xor(v, 32);
      if ((t & 63) == 0) gred[t >> 6][n] = v;
    }
    __syncthreads();
    if (t < 12) {
      float s4 = gred[0][t] + gred[1][t] + gred[2][t] + gred[3][t];
      gate[(long)row * 12 + t] = 1.f / (1.f + __expf(-(s4 + gb[t])));
    }
  }
}

// ======== 256x256 8-phase GEMM, BK=32, 8 waves, 64KB LDS (round-10 proven, sound sync) ========
// Counted vmcnt(2) is per-wave: always followed by a barrier before any wave reads
// the staged tile (each wave drains its own loads; barrier => ALL loads landed).
template <int EPI, int KT, int LD, int NKS>
__global__ __launch_bounds__(512) void gemm256(
    const bf16* __restrict__ A, const bf16* __restrict__ Bt, void* __restrict__ Out,
    const float* __restrict__ resid, const float* __restrict__ scale,
    int N, int nbn, int Mreal, bf16* __restrict__ alt3) {
  __shared__ __align__(16) bf16 lds[2][4][128 * 32];   // 64 KB
  int tid = threadIdx.x;
  int lane = tid & 63, wid = tid >> 6;
  int wr = wid >> 2, wc = wid & 3;         // wave grid 2(M) x 4(N)
  int lr = lane & 15, lg = lane >> 4;

  // XCD-bijective block swizzle (m204)
  int nwg = gridDim.x;
  int bid = blockIdx.x;
  int q = nwg >> 3, r8 = nwg & 7;
  int xcd = bid & 7, idx = bid >> 3;
  int wg = (xcd < r8 ? xcd * (q + 1) : r8 * (q + 1) + (xcd - r8) * q) + idx;

  int ks = 0;
  if (NKS > 1) {
    int bps = nwg / NKS;                   // blocks per k-slice
    ks = wg / bps;
    wg = wg - ks * bps;
    A += (long)ks * KT * 32;
    Bt += (long)ks * KT * 32;
  }
  int bm = wg / nbn, bn = wg - bm * nbn;

  // hoisted ds-read base pointers: (row>>1)&3 == (lr>>1)&3 for every fragment row
  const bf16 *aP[2], *bP[2];
  {
    int off = lr * 32 + ((lg ^ ((lr >> 1) & 3)) * 8);
#pragma unroll
    for (int b = 0; b < 2; b++) {
      aP[b] = &lds[b][wr][off];
      bP[b] = &lds[b][2 + (wc >> 1)][(wc & 1) * 2048 + off];
    }
  }
  // hoisted staging pointers (inverse-swizzled global source)
  int srow = tid >> 2;                         // 0..127
  int cc = (tid & 3) ^ ((srow >> 1) & 3);
  const bf16 *aB[2], *bB[2];
#pragma unroll
  for (int h = 0; h < 2; h++) {
    aB[h] = A + ((long)bm * 256 + h * 128 + srow) * LD + cc * 8;
    bB[h] = Bt + ((long)bn * 256 + h * 128 + srow) * LD + cc * 8;
  }

#define STA(buf, half, kt) gload_lds16(aB[half] + (kt) * 32, &lds[buf][half][tid * 8]);
#define STB(buf, half, kt) gload_lds16(bB[half] + (kt) * 32, &lds[buf][2 + (half)][tid * 8]);

  f32x4 z; z[0] = z[1] = z[2] = z[3] = 0.f;
  f32x4 acc[8][4];
#pragma unroll
  for (int mi = 0; mi < 8; mi++)
#pragma unroll
    for (int ni = 0; ni < 4; ni++) acc[mi][ni] = z;

  bf16x8v bf[4];
  bf16x8v af[2];

  // prologue: tile0 full + tile1 B-halves (6 insts; vmcnt2 then barrier -> sound)
  STA(0, 0, 0); STA(0, 1, 0); STB(0, 0, 0); STB(0, 1, 0);
  STB(1, 0, 1); STB(1, 1, 1);
  VMCNT2;
  BARRIER;

#define PHASE(p, bb, STG, VM)                                                   \
  {                                                                             \
    if ((p) == 0) {                                                             \
      _Pragma("unroll") for (int ni = 0; ni < 4; ni++)                          \
        bf[ni] = *(const bf16x8v*)(bP[bb] + ni * 512);                          \
    }                                                                           \
    af[0] = *(const bf16x8v*)(aP[bb] + (2 * (p)) * 512);                        \
    af[1] = *(const bf16x8v*)(aP[bb] + (2 * (p) + 1) * 512);                    \
    STG;                                                                        \
    BARRIER;                                                                    \
    __builtin_amdgcn_s_setprio(1);                                              \
    _Pragma("unroll") for (int dm = 0; dm < 2; dm++)                            \
      _Pragma("unroll") for (int ni = 0; ni < 4; ni++)                          \
        acc[2 * (p) + dm][ni] = __builtin_amdgcn_mfma_f32_16x16x32_bf16(        \
            af[dm], bf[ni], acc[2 * (p) + dm][ni], 0, 0, 0);                    \
    __builtin_amdgcn_s_setprio(0);                                              \
    if (VM) { VMCNT2; BARRIER; }                                                \
  }

#define ITERBODY(i)                                                             \
  {                                                                             \
    int u = 2 * (i) + 1;                                                        \
    int t2 = (2 * (i) + 2 < KT) ? 2 * (i) + 2 : KT - 1;                         \
    int t3 = (2 * (i) + 3 < KT) ? 2 * (i) + 3 : KT - 1;                         \
    PHASE(0, 0, STA(1, 0, u), 0);                                               \
    PHASE(1, 0, STA(1, 1, u), 0);                                               \
    PHASE(2, 0, STB(0, 0, t2), 0);                                              \
    PHASE(3, 0, STB(0, 1, t2), 1);                                              \
    PHASE(0, 1, STA(0, 0, t2), 0);                                              \
    PHASE(1, 1, STA(0, 1, t2), 0);                                              \
    PHASE(2, 1, STB(1, 0, t3), 0);                                              \
    PHASE(3, 1, STB(1, 1, t3), 1);                                              \
  }

  if (KT <= 12) {
#pragma unroll
    for (int i = 0; i < KT / 2; i++) ITERBODY(i);
  } else {
#pragma unroll 2
    for (int i = 0; i < KT / 2; i++) ITERBODY(i);
  }
  VMCNT0;   // drain redundant tail stages: nothing in flight at exit
#undef ITERBODY
#undef PHASE
#undef STA
#undef STB

  // epilogue
  long rowbase = (long)bm * 256 + wr * 128;
  int colbase = bn * 256 + wc * 64;
  if (EPI == 0) {
    bf16* O;
    if (NKS > 1) O = (ks < 3) ? (bf16*)Out + (long)ks * PSLICE : alt3;
    else O = (bf16*)Out;
#pragma unroll
    for (int mi = 0; mi < 8; mi++)
#pragma unroll
      for (int ni = 0; ni < 4; ni++)
#pragma unroll
        for (int r = 0; r < 4; r++)
          O[(rowbase + mi * 16 + lg * 4 + r) * N + colbase + ni * 16 + lr] =
              __float2bfloat16(acc[mi][ni][r]);
  } else if (EPI == 1) {
    float* O = (float*)Out;
#pragma unroll
    for (int ni = 0; ni < 4; ni++) {
      float sc = scale[colbase + ni * 16 + lr];
#pragma unroll
      for (int mi = 0; mi < 8; mi++)
#pragma unroll
        for (int r = 0; r < 4; r++) {
          long row = rowbase + mi * 16 + lg * 4 + r;
          long col = colbase + ni * 16 + lr;
          if (row < Mreal)
            O[row * N + col] = resid[row * N + col] + acc[mi][ni][r] * sc;
        }
    }
  } else {
    bf16* O = (bf16*)Out;
    int oc0 = colbase >> 1;
#pragma unroll
    for (int mi = 0; mi < 8; mi++)
#pragma unroll
      for (int p = 0; p < 2; p++)
#pragma unroll
        for (int r = 0; r < 4; r++) {
          float g = acc[mi][2 * p][r], u = acc[mi][2 * p + 1][r];
          float v = g / (1.f + __expf(-g)) * u;
          O[(rowbase + mi * 16 + lg * 4 + r) * 2048 + oc0 + p * 16 + lr] =
              __float2bfloat16(v);
        }
  }
}

// ---------------- MLP2 split-K reduce: out = x2 + (P0+P1+P2+P3)*mscale ----------------
__global__ __launch_bounds__(256) void mlp2_reduce(
    const bf16* __restrict__ p012, const bf16* __restrict__ p3,
    const float* __restrict__ x2, const float* __restrict__ mscale,
    float* __restrict__ out) {
  long i = (long)blockIdx.x * 256 + threadIdx.x;
  long row = i / 96;
  int c8 = (int)(i - row * 96) * 8;
  long off = row * 768 + c8;
  float a[8];
#pragma unroll
  for (int j = 0; j < 8; j++) a[j] = 0.f;
#pragma unroll
  for (int s = 0; s < 3; s++) {
    bf16x8v v = *(const bf16x8v*)(p012 + s * PSLICE + off);
#pragma unroll
    for (int j = 0; j < 8; j++) {
      short sv = v[j];
      a[j] += __bfloat162float(*reinterpret_cast<bf16*>(&sv));
    }
  }
  {
    bf16x8v v = *(const bf16x8v*)(p3 + off);
#pragma unroll
    for (int j = 0; j < 8; j++) {
      short sv = v[j];
      a[j] += __bfloat162float(*reinterpret_cast<bf16*>(&sv));
    }
  }
#pragma unroll
  for (int j = 0; j < 8; j++)
    out[off + j] = x2[off + j] + a[j] * mscale[c8 + j];
}

// ---------------- V transpose: qkv v-part -> vtf[(bh*64+d)*SP_+s]; zero pad cols ----------------
__global__ __launch_bounds__(256) void vtran(const bf16* __restrict__ qkv, bf16* __restrict__ vtf) {
  __shared__ bf16 tile[32][66];
  int st = blockIdx.x, bh = blockIdx.y;
  int bb = bh / NH_, h = bh - bb * NH_;
  int s0 = st * 32;
  int t = threadIdx.x;
  int si = t >> 6, d = t & 63;
#pragma unroll
  for (int i = 0; i < 8; i++) {
    int s = s0 + i * 4 + si;
    bf16 v = __float2bfloat16(0.f);
    if (s < S_) v = qkv[(long)(bb * S_ + s) * 2304 + 1536 + h * 64 + d];
    tile[i * 4 + si][d] = v;
  }
  __syncthreads();
  int dd = t >> 5, sj = t & 31;
#pragma unroll
  for (int i = 0; i < 8; i++) {
    int d2 = i * 8 + dd;
    vtf[((long)bh * 64 + d2) * SP_ + s0 + sj] = tile[sj][d2];
  }
}

// ---------------- qk rmsnorm + rope + scale (q scaled to base-2 exp units) ----------------
__global__ __launch_bounds__(768) void qkv_post(
    const bf16* __restrict__ qkv, const float* __restrict__ qw, const float* __restrict__ kw,
    const float* __restrict__ cosT, const float* __restrict__ sinT,
    bf16* __restrict__ qf, bf16* __restrict__ kf) {
  int tok = blockIdx.x;
  int bb = tok / S_, s = tok - bb * S_;
  int h = threadIdx.x >> 6, d = threadIdx.x & 63;
  const bf16* base = qkv + (long)tok * 2304 + h * 64 + d;
  float q = __bfloat162float(base[0]);
  float k = __bfloat162float(base[768]);
  float qs = q * q, ks = k * k;
  for (int off = 32; off; off >>= 1) {
    qs += __shfl_xor(qs, off);
    ks += __shfl_xor(ks, off);
  }
  q *= rsqrtf(qs * (1.f / 64.f) + EPS_) * qw[d];
  k *= rsqrtf(ks * (1.f / 64.f) + EPS_) * kw[d];
  if (s >= S_ - 1024) {
    int pos = s - (S_ - 1024);
    int i = d >> 1;
    float c = cosT[pos * 32 + i], sn = sinT[pos * 32 + i];
    float qp = __shfl_xor(q, 1), kp = __shfl_xor(k, 1);
    if (d & 1) { q = qp * sn + q * c; k = kp * sn + k * c; }
    else       { q = q * c - qp * sn; k = k * c - kp * sn; }
  }
  q *= 0.125f * 1.44269504088896f;  // fold log2(e): softmax done in base 2
  long o1 = ((long)(bb * NH_ + h) * SP_ + s) * 64 + d;
  qf[o1] = __float2bfloat16(q);
  kf[o1] = __float2bfloat16(k);
}

// swizzled LDS element offset for a [64][8x(8elem)] bf16 tile: row, colchunk cc
#define SWZ(row, cc) (((row) << 6) + ((((cc) ^ ((row) & 7))) << 3))

// ---------------- flash attention: 4 waves/block, 64 q-rows, KVBLK=64, LDS dbuf ----------------
// (round-10 proven config: 32 KB LDS, ~12 waves/CU)
// UNNORMALIZED softmax: after qk-rmsnorm ||q||=||k||=8 (RoPE is a rotation), so by
// Cauchy-Schwarz |score_base2| <= 8*8*0.125*log2(e) = 11.5 -> exp2 in [2^-11.5, 2^11.5],
// lsum in [0.36, 3.1e6]: no overflow, identical relative error. No max tracking needed.
__global__ __launch_bounds__(256) void attn_k(
    const bf16* __restrict__ qf, const bf16* __restrict__ kf, const bf16* __restrict__ vtf,
    const float* __restrict__ gate, bf16* __restrict__ attn_g) {
  __shared__ __align__(16) bf16 Ks[2][64 * 64];
  __shared__ __align__(16) bf16 Vs[2][64 * 64];
  int bid = blockIdx.x;                      // 1632 = 8 * 204
  int w = (bid & 7) * 204 + (bid >> 3);      // XCD-pinned: 12 bh per XCD
  int bh = w / 17, qb = w - bh * 17;
  int bb = bh / NH_, h = bh - bb * NH_;
  int tid = threadIdx.x;
  int lane = tid & 63, wv = tid >> 6;
  int lr = lane & 15, lg = lane >> 4;
  const bf16* qbase = qf + (long)bh * SP_ * 64;
  const bf16* kbase = kf + (long)bh * SP_ * 64;
  const bf16* vbase = vtf + (long)bh * 64 * SP_;

  int q_l = qb * 64 + wv * 16 + lr;          // q row this lane owns
  bf16x8v qB0 = *(const bf16x8v*)(qbase + (long)q_l * 64 + lg * 8);
  bf16x8v qB1 = *(const bf16x8v*)(qbase + (long)q_l * 64 + 32 + lg * 8);

  f32x4 z; z[0] = z[1] = z[2] = z[3] = 0.f;
  f32x4 acc[4] = {z, z, z, z};
  float tsacc = 0.f;                         // per-lane partial sum (16 of 64 ks per tile)

  auto stage = [&](int buf, int kidx) {
#pragma unroll
    for (int inst = 0; inst < 2; inst++) {
      int c = inst * 256 + tid;
      int row = c >> 3, slot = c & 7;
      int cc = slot ^ (row & 7);
      gload_lds16(kbase + (long)(kidx + row) * 64 + cc * 8, &Ks[buf][c * 8]);
    }
#pragma unroll
    for (int inst = 0; inst < 2; inst++) {
      int c = inst * 256 + tid;
      int row = c >> 3, slot = c & 7;
      int cc = slot ^ (row & 7);
      gload_lds16(vbase + (long)row * SP_ + kidx + cc * 8, &Vs[buf][c * 8]);
    }
  };

  stage(0, 0);
  VMCNT0;
  __syncthreads();
  int cur = 0;

  for (int kt = 0; kt < SP_ / 64; kt++) {
    int kidx = kt * 64;
    if (kt < SP_ / 64 - 1) stage(cur ^ 1, kidx + 64);

    f32x4 p[4];
    __builtin_amdgcn_s_setprio(1);
#pragma unroll
    for (int mt = 0; mt < 4; mt++) {
      int row = mt * 16 + lr;
      bf16x8v k0 = *(const bf16x8v*)&Ks[cur][SWZ(row, lg)];
      bf16x8v k1 = *(const bf16x8v*)&Ks[cur][SWZ(row, lg + 4)];
      f32x4 t = z;
      t = __builtin_amdgcn_mfma_f32_16x16x32_bf16(k0, qB0, t, 0, 0, 0);
      t = __builtin_amdgcn_mfma_f32_16x16x32_bf16(k1, qB1, t, 0, 0, 0);
      p[mt] = t;
    }
    __builtin_amdgcn_s_setprio(0);

    if (kidx + 64 > S_) {
#pragma unroll
      for (int mt = 0; mt < 4; mt++)
#pragma unroll
        for (int r = 0; r < 4; r++)
          if (kidx + mt * 16 + lg * 4 + r >= S_) p[mt][r] = -1e30f;
    }

    // unnormalized: p = exp2(score), accumulate per-lane partial sum
#pragma unroll
    for (int mt = 0; mt < 4; mt++)
#pragma unroll
      for (int r = 0; r < 4; r++) {
        float e = exp2f(p[mt][r]);
        p[mt][r] = e;
        tsacc += e;
      }

    uint32_t w0[4], w1[4];
#pragma unroll
    for (int mt = 0; mt < 4; mt++) {
      asm("v_cvt_pk_bf16_f32 %0, %1, %2" : "=v"(w0[mt]) : "v"(p[mt][0]), "v"(p[mt][1]));
      asm("v_cvt_pk_bf16_f32 %0, %1, %2" : "=v"(w1[mt]) : "v"(p[mt][2]), "v"(p[mt][3]));
    }
    bf16x8v aP[2];
#pragma unroll
    for (int t2 = 0; t2 < 2; t2++) {
      union { uint32_t u[4]; bf16x8v v; } cvt;
#pragma unroll
      for (int wd = 0; wd < 4; wd++) {
        uint32_t a = (wd & 1) ? w1[2 * t2] : w0[2 * t2];
        uint32_t b = (wd & 1) ? w1[2 * t2 + 1] : w0[2 * t2 + 1];
        uint32_t val = (lg & 2) ? b : a;
        int src = ((lg & 1) * 2 + (wd >> 1)) * 16 + lr;
        cvt.u[wd] = (uint32_t)__shfl((int)val, src);
      }
      aP[t2] = cvt.v;
    }
    __builtin_amdgcn_s_setprio(1);
#pragma unroll
    for (int t2 = 0; t2 < 2; t2++)
#pragma unroll
      for (int dt = 0; dt < 4; dt++) {
        int row = dt * 16 + lr;
        bf16x8v vB = *(const bf16x8v*)&Vs[cur][SWZ(row, t2 * 4 + lg)];
        acc[dt] = __builtin_amdgcn_mfma_f32_16x16x32_bf16(aP[t2], vB, acc[dt], 0, 0, 0);
      }
    __builtin_amdgcn_s_setprio(0);

    VMCNT0;
    __syncthreads();
    cur ^= 1;
  }

  // single cross-lane lsum reduce at the end
  tsacc += __shfl_xor(tsacc, 16);
  tsacc += __shfl_xor(tsacc, 32);
  float norm = 0.f;
  if (q_l < S_) norm = gate[((long)bb * S_ + q_l) * 12 + h] / tsacc;
  float nr[4];
#pragma unroll
  for (int r = 0; r < 4; r++) nr[r] = __shfl(norm, lg * 4 + r);
#pragma unroll
  for (int dt = 0; dt < 4; dt++)
#pragma unroll
    for (int r = 0; r < 4; r++) {
      int qr = qb * 64 + wv * 16 + lg * 4 + r;
      if (qr < S_)
        attn_g[((long)bb * S_ + qr) * H_ + h * 64 + dt * 16 + lr] =
            __float2bfloat16(acc[dt][r] * nr[r]);
    }
}

extern "C" void kernel_launch(void* const* d_in, const int* in_sizes, int n_in,
                              void* d_out, int out_size, void* d_ws, size_t ws_size,
                              hipStream_t stream) {
  const float* x    = (const float*)d_in[0];
  const float* cosT = (const float*)d_in[1];
  const float* sinT = (const float*)d_in[2];
  const float* Wq   = (const float*)d_in[3];
  const float* Wk   = (const float*)d_in[4];
  const float* Wv   = (const float*)d_in[5];
  const float* Wo   = (const float*)d_in[6];
  const float* qnw  = (const float*)d_in[7];
  const float* knw  = (const float*)d_in[8];
  const float* gW   = (const float*)d_in[9];
  const float* gb   = (const float*)d_in[10];
  const float* n1w  = (const float*)d_in[11];
  const float* n2w  = (const float*)d_in[12];
  const float* Wg   = (const float*)d_in[13];
  const float* Wu   = (const float*)d_in[14];
  const float* Wd   = (const float*)d_in[15];
  const float* ascale = (const float*)d_in[16];
  const float* mscale = (const float*)d_in[17];

  char* ws = (char*)d_ws;
  size_t off = 0;
  auto alloc = [&](size_t bytes) {
    char* p = ws + off;
    off += (bytes + 255) & ~(size_t)255;
    return p;
  };
  bf16* h_pad  = (bf16*)alloc((size_t)MP_ * H_ * 2);      // reused as h2
  bf16* wqkv_t = (bf16*)alloc((size_t)2304 * 768 * 2);
  bf16* wo_t   = (bf16*)alloc((size_t)768 * 768 * 2);
  bf16* wgu_t  = (bf16*)alloc((size_t)4096 * 768 * 2);    // gate/up 16-col interleaved
  bf16* wdn_t  = (bf16*)alloc((size_t)768 * 2048 * 2);
  bf16* qkv    = (bf16*)alloc((size_t)MP_ * 2304 * 2);    // reused as mlpin (MP_*2048)
  bf16* qfb    = (bf16*)alloc((size_t)PSLICE * 2);        // reused: MLP2 partial 0
  bf16* kfb    = (bf16*)alloc((size_t)PSLICE * 2);        // reused: MLP2 partial 1
  bf16* vtfb   = (bf16*)alloc((size_t)PSLICE * 2);        // reused: MLP2 partial 2
  float* gateb = (float*)alloc((size_t)T_ * 12 * 4);
  bf16* attn_g = (bf16*)alloc((size_t)MP_ * H_ * 2);      // reused: MLP2 partial 3
  float* x2    = (float*)alloc((size_t)T_ * H_ * 4);
  bf16* mlpin  = qkv;

  // weight conversion
  auto wc = [&](const float* W, bf16* o, int K, int N) {
    wcvt_t<<<dim3(K / 32, N / 32), 256, 0, stream>>>(W, o, K, N);
  };
  wc(Wq, wqkv_t, 768, 768);
  wc(Wk, wqkv_t + 768 * 768, 768, 768);
  wc(Wv, wqkv_t + 2 * 768 * 768, 768, 768);
  wc(Wo, wo_t, 768, 768);
  wc(Wd, wdn_t, 2048, 768);
  wcvt_gu<<<dim3(24, 128), 256, 0, stream>>>(Wg, Wu, wgu_t);

  rmsnorm_k<1><<<MP_, 256, 0, stream>>>(x, n1w, h_pad, gW, gb, gateb, T_);

  // QKV: M=8448 N=2304 K=768
  gemm256<0, 24, 768, 1><<<9 * 33, 512, 0, stream>>>(h_pad, wqkv_t, qkv, nullptr, nullptr,
                                                     2304, 9, MP_, nullptr);

  qkv_post<<<T_, 768, 0, stream>>>(qkv, qnw, knw, cosT, sinT, qfb, kfb);
  vtran<<<dim3(34, 96), 256, 0, stream>>>(qkv, vtfb);

  attn_k<<<1632, 256, 0, stream>>>(qfb, kfb, vtfb, gateb, attn_g);

  // Wo: M=8448 N=768 K=768, fp32 resid+scale epilogue
  gemm256<1, 24, 768, 1><<<3 * 33, 512, 0, stream>>>(attn_g, wo_t, x2, x, ascale,
                                                     768, 3, T_, nullptr);

  rmsnorm_k<0><<<MP_, 256, 0, stream>>>(x2, n2w, h_pad, nullptr, nullptr, nullptr, T_);

  // MLP1: M=8448 N=4096 K=768, silu-fused
  gemm256<2, 24, 768, 1><<<16 * 33, 512, 0, stream>>>(h_pad, wgu_t, mlpin, nullptr, nullptr,
                                                      4096, 16, MP_, nullptr);

  // MLP2: split-K=4 (slice K=512, KT=16), 396 blocks; bf16 partials -> reduce
  gemm256<0, 16, 2048, 4><<<4 * 3 * 33, 512, 0, stream>>>(mlpin, wdn_t, qfb, nullptr, nullptr,
                                                          768, 3, MP_, attn_g);
  mlp2_reduce<<<(T_ * 96) / 256, 256, 0, stream>>>(qfb, attn_g, x2, mscale, (float*)d_out);
}